// Round 8
// baseline (556.904 us; speedup 1.0000x reference)
//
#include <hip/hip_runtime.h>
#include <hip/hip_bf16.h>

// Problem constants (B=2, S=2048, D=1536, H=12, hd=128)
#define S_LEN   2048
#define DMODEL  1536
#define NBATCH  2
#define NHEADS  12
#define MROWS   (NBATCH * S_LEN)        // 4096
#define NCHUNK  64                      // scan chunks per sequence (32 rows each)
#define CHUNK   32

#define NGEMM_BLK  384                  // (MROWS/128) * (DMODEL/128) = 32*12
#define AW_BLK     3072                 // aw writer blocks per GEMM launch
#define WA_BLK     3072                 // winavg blocks
#define AW_BLK_W   512                  // aw writer blocks in winavg launch

// attn_weights f32x4 elements: B*H*S*S/4, split 45% / 15% / 40%
#define AW_TOT4    25165824u
#define AW1_END    11324416u            // gemm1 slice  [0, AW1_END)
#define AWW_END    15098880u            // winavg slice [AW1_END, AWW_END)

typedef unsigned short u16;
typedef __attribute__((ext_vector_type(8))) short bf16x8;   // 8 bf16 = 4 VGPRs
typedef __attribute__((ext_vector_type(4))) float f32x4;    // native vec4

// round-to-nearest-even fp32 -> bf16
__device__ __forceinline__ u16 f2bf(float x) {
  unsigned u = __float_as_uint(x);
  u += 0x7fffu + ((u >> 16) & 1u);
  return (u16)(u >> 16);
}
__device__ __forceinline__ float bf2f(u16 x) {
  return __uint_as_float(((unsigned)x) << 16);
}

// analytic attn_weights writer: grid-stride over [aw0, aw0+awcnt) f32x4 slots
// R8 A/B: PLAIN stores (NT reverted) — m13's 6.29 TB/s ceiling was measured
// with plain stores; testing whether NT write-around was throttling the stream.
__device__ __forceinline__ void aw_write(f32x4* __restrict__ aw, unsigned aw0,
                                         unsigned awcnt, unsigned bid,
                                         unsigned nblk) {
  const unsigned stride = nblk * 256u;
  const unsigned end = aw0 + awcnt;
  for (unsigned t = aw0 + bid * 256u + threadIdx.x; t < end; t += stride) {
    int j0 = (int)(t & 511u) << 2;
    int i  = (int)(t >> 9) & (S_LEN - 1);
    int bh = (int)(t >> 20);                     // S*S/4 = 2^20 per (b,h)
    int h  = bh >= NHEADS ? bh - NHEADS : bh;
    int w  = (2 << h) - 1;
    float inv = 1.0f / (float)min(i + 1, w);
    int lo = i - w + 1;
    f32x4 r;
    r.x = (j0     <= i && j0     >= lo) ? inv : 0.f;
    r.y = (j0 + 1 <= i && j0 + 1 >= lo) ? inv : 0.f;
    r.z = (j0 + 2 <= i && j0 + 2 >= lo) ? inv : 0.f;
    r.w = (j0 + 3 <= i && j0 + 3 >= lo) ? inv : 0.f;
    aw[t] = r;
  }
}

// ---------------------------------------------------------------- fused cvt fp32->bf16 (3 tensors)
#define N4_HID  1572864     // 2*2048*1536/4
#define N4_W    589824      // 1536*1536/4
__global__ void cvt_all(const float4* __restrict__ h, const float4* __restrict__ wf,
                        const float4* __restrict__ wp, ushort4* __restrict__ ho,
                        ushort4* __restrict__ wfo, ushort4* __restrict__ wpo) {
  int t = blockIdx.x * blockDim.x + threadIdx.x;   // N4_HID + 2*N4_W = 2752512
  const float4* src;
  ushort4* dst;
  int idx;
  if (t < N4_HID)            { src = h;  dst = ho;  idx = t; }
  else if (t < N4_HID + N4_W){ src = wf; dst = wfo; idx = t - N4_HID; }
  else                       { src = wp; dst = wpo; idx = t - N4_HID - N4_W; }
  float4 f = src[idx];
  ushort4 o;
  o.x = f2bf(f.x); o.y = f2bf(f.y); o.z = f2bf(f.z); o.w = f2bf(f.w);
  dst[idx] = o;
}

// ---------------------------------------------------------------- GEMM + attn-weights hybrid
// Blocks [0, NGEMM_BLK): m97-structure bf16 GEMM C = A@B^T + bias (128x128
// tile, BK=32, 4 waves, 16x16x32 MFMA, global_load_lds width=16).
// Blocks [NGEMM_BLK, ...): attn-weights stream (co-scheduled, m114).
__device__ __forceinline__ void gld_lds16(u16* lds, const u16* g) {
  __builtin_amdgcn_global_load_lds(
      (const __attribute__((address_space(1))) unsigned int*)g,
      (__attribute__((address_space(3))) unsigned int*)lds, 16, 0, 0);
}

template <bool WITH_CSUM, typename CT>
__global__ __launch_bounds__(256)
void gemm_aw(const u16* __restrict__ A, const u16* __restrict__ B,
             const float* __restrict__ bias, CT* __restrict__ C,
             float* __restrict__ cs, f32x4* __restrict__ aw,
             unsigned aw0, unsigned awcnt, int Ndim, int Kdim) {
  if ((int)blockIdx.x >= NGEMM_BLK) {
    aw_write(aw, aw0, awcnt, blockIdx.x - NGEMM_BLK, gridDim.x - NGEMM_BLK);
    return;
  }

  __shared__ __align__(16) u16 As[128 * 32];   // row-major, row stride 32 bf16 (64 B)
  __shared__ __align__(16) u16 Bs[128 * 32];
  __shared__ float colpart[4][128];            // 32-row-group column sums

  const int tid  = threadIdx.x;
  const int wave = tid >> 6;
  const int lane = tid & 63;
  const int l15  = lane & 15;
  const int quad = lane >> 4;
  const int bm = (blockIdx.x / (DMODEL / 128)) * 128;
  const int bn = (blockIdx.x % (DMODEL / 128)) * 128;
  const int wm = (wave >> 1) * 64;
  const int wn = (wave & 1) * 64;

  f32x4 acc[4][4] = {};

  const int srow = wave * 32 + (lane >> 2);
  const int skk  = (lane & 3) * 8;
  const u16* gA = A + (size_t)(bm + srow) * Kdim + skk;
  const u16* gB = B + (size_t)(bn + srow) * Kdim + skk;
  u16* lA = &As[(wave * 32) * 32];
  u16* lB = &Bs[(wave * 32) * 32];
  const size_t rstep16 = (size_t)16 * Kdim;

  for (int k0 = 0; k0 < Kdim; k0 += 32) {
    gld_lds16(lA,           gA + k0);
    gld_lds16(lA + 16 * 32, gA + k0 + rstep16);
    gld_lds16(lB,           gB + k0);
    gld_lds16(lB + 16 * 32, gB + k0 + rstep16);
    __syncthreads();

    bf16x8 af[4], bfr[4];
#pragma unroll
    for (int i = 0; i < 4; ++i)
      af[i] = *(const bf16x8*)&As[(wm + i * 16 + l15) * 32 + quad * 8];
#pragma unroll
    for (int j = 0; j < 4; ++j)
      bfr[j] = *(const bf16x8*)&Bs[(wn + j * 16 + l15) * 32 + quad * 8];
#pragma unroll
    for (int i = 0; i < 4; ++i)
#pragma unroll
      for (int j = 0; j < 4; ++j)
        acc[i][j] = __builtin_amdgcn_mfma_f32_16x16x32_bf16(af[i], bfr[j], acc[i][j], 0, 0, 0);
    __syncthreads();
  }

  // epilogue: C/D layout col = lane&15, row = quad*4 + reg   [verified m89/m91]
  const int r0 = quad * 4;
#pragma unroll
  for (int j = 0; j < 4; ++j) {
    const int col = bn + wn + j * 16 + l15;
    const float bj = bias[col];
    float sA = 0.f, sB = 0.f;     // rows [wm, wm+32) and [wm+32, wm+64)
#pragma unroll
    for (int i = 0; i < 4; ++i) {
      const int row = bm + wm + i * 16 + r0;
#pragma unroll
      for (int r = 0; r < 4; ++r) {
        float cv = acc[i][j][r] + bj;
        if constexpr (sizeof(CT) == 2)
          C[(size_t)(row + r) * Ndim + col] = (CT)f2bf(cv);
        else
          C[(size_t)(row + r) * Ndim + col] = (CT)cv;   // plain store (NT reverted)
        if (WITH_CSUM) { if (i < 2) sA += cv; else sB += cv; }
      }
    }
    if (WITH_CSUM) {
      sA += __shfl_xor(sA, 16); sA += __shfl_xor(sA, 32);
      sB += __shfl_xor(sB, 16); sB += __shfl_xor(sB, 32);
      if (quad == 0) {
        colpart[(wm >> 5) | 0][wn + j * 16 + l15] = sA;
        colpart[(wm >> 5) | 1][wn + j * 16 + l15] = sB;
      }
    }
  }
  if (WITH_CSUM) {
    __syncthreads();
    if (tid < 128) {
      const int b  = bm >> 11;               // 2048 rows per batch
      const int c0 = (bm & 2047) >> 5;       // first 32-row chunk of this tile
#pragma unroll
      for (int g = 0; g < 4; ++g)
        cs[((size_t)b * NCHUNK + c0 + g) * DMODEL + bn + tid] = colpart[g][tid];
    }
  }
}

// ---------------------------------------------------------------- winavg (strip=8) + aw hybrid
// Blocks [0, WA_BLK): one thread per (b, 8-row strip, d). Chunk prefix is
// inlined: E[c0] and E[ct] (ct<=c0) accumulate in ONE pass of <=63
// INDEPENDENT L2-resident csums loads (no dependent chain, no Epre buffer).
// Blocks [WA_BLK, ...): attn-weights stream under winavg's latency-bound
// execution (spare HBM write BW). Branches wave-uniform.
__global__ void winavg_aw(const u16* __restrict__ v, const float* __restrict__ cs,
                          u16* __restrict__ A2, f32x4* __restrict__ aw,
                          unsigned aw0, unsigned awcnt) {
  if ((int)blockIdx.x >= WA_BLK) {
    aw_write(aw, aw0, awcnt, blockIdx.x - WA_BLK, gridDim.x - WA_BLK);
    return;
  }
  int t = blockIdx.x * blockDim.x + threadIdx.x;   // NBATCH*(S_LEN/8)*DMODEL = 786432
  int d = t % DMODEL;
  int s = (t / DMODEL) & 255;                      // strip index, S_LEN/8 = 256
  int b = t / (DMODEL * 256);
  const int h = d >> 7;
  const int w = (2 << h) - 1;                      // 2^(h+1)-1
  const u16* vb   = v  + (size_t)b * S_LEN * DMODEL + d;
  const float* csb = cs + (size_t)b * NCHUNK * DMODEL + d;

  const int i0 = s * 8;
  const int c0 = i0 >> 5;                          // lead chunk
  const bool need_trail = (i0 + 7 >= w);           // wave-uniform
  const int jf = max(i0, w) - w;                   // first trail row consumed
  const int ct = (need_trail && jf > 0) ? ((jf - 1) >> 5) : 0;   // <= c0

  // one pass: E0 = E[c0], Et = E[ct]
  float E0 = 0.f, Et = 0.f;
  for (int cc = 0; cc < c0; ++cc) {                // uniform trip, independent loads
    float cv = csb[(size_t)cc * DMODEL];
    E0 += cv;
    if (cc < ct) Et += cv;
  }

  // lead = P[i0-1]
  float lead = E0;
  for (int r = c0 * 32; r < i0; ++r)               // trip in {0,8,16,24}, uniform
    lead += bf2f(vb[(size_t)r * DMODEL]);

  // trail = P[jf-1]
  float trail = 0.f;
  if (need_trail && jf > 0) {
    trail = Et;
    for (int r = ct * 32; r < jf; ++r)             // trip <=32, uniform
      trail += bf2f(vb[(size_t)r * DMODEL]);
  }

  u16* out = A2 + ((size_t)(b * S_LEN + i0)) * DMODEL + d;
#pragma unroll
  for (int rr = 0; rr < 8; ++rr) {
    const int i = i0 + rr;
    lead += bf2f(vb[(size_t)i * DMODEL]);          // lead = P[i]
    float o;
    if (i < w) {                                   // window not yet full (uniform)
      o = lead / (float)(i + 1);
    } else {
      trail += bf2f(vb[(size_t)(i - w) * DMODEL]); // trail = P[i-w]
      o = (lead - trail) / (float)w;
    }
    out[(size_t)rr * DMODEL] = f2bf(o);
  }
}

// ---------------------------------------------------------------- launch
extern "C" void kernel_launch(void* const* d_in, const int* in_sizes, int n_in,
                              void* d_out, int out_size, void* d_ws, size_t ws_size,
                              hipStream_t stream) {
  const float* hidden = (const float*)d_in[0];
  const float* W_fc   = (const float*)d_in[1];
  const float* b_fc   = (const float*)d_in[2];
  const float* W_proj = (const float*)d_in[3];
  const float* b_proj = (const float*)d_in[4];
  float* outp = (float*)d_out;
  f32x4* aw = (f32x4*)(outp + (size_t)MROWS * DMODEL);

  // workspace layout (bytes), total 35.4 MB:
  //   0        : A16   (12,582,912)  hidden bf16, later reused as winavg-output bf16
  //   12582912 : Wfc16 ( 4,718,592)
  //   17301504 : Wpj16 ( 4,718,592)
  //   22020096 : v16   (12,582,912)  bf16 v from GEMM1
  //   34603008 : csums (   786,432)  [B, NCHUNK, D] fp32 32-row chunk sums
  char* ws = (char*)d_ws;
  u16*   A16   = (u16*)(ws);
  u16*   Wfc16 = (u16*)(ws + 12582912);
  u16*   Wpj16 = (u16*)(ws + 17301504);
  u16*   v16   = (u16*)(ws + 22020096);
  float* csums = (float*)(ws + 34603008);

  // 1) all fp32->bf16 conversions in one launch
  cvt_all<<<10752, 256, 0, stream>>>((const float4*)hidden, (const float4*)W_fc,
                                     (const float4*)W_proj, (ushort4*)A16,
                                     (ushort4*)Wfc16, (ushort4*)Wpj16);

  // 2) GEMM1 (v -> bf16, fused chunk sums) + 45% of attn_weights
  gemm_aw<true, u16><<<NGEMM_BLK + AW_BLK, 256, 0, stream>>>(
      A16, Wfc16, b_fc, v16, csums, aw, 0u, AW1_END, DMODEL, DMODEL);

  // 3) winavg (inline chunk prefix) + 15% of attn_weights
  winavg_aw<<<WA_BLK + AW_BLK_W, 256, 0, stream>>>(
      v16, csums, A16, aw, AW1_END, AWW_END - AW1_END);

  // 4) GEMM2 (out -> d_out fp32) + 40% of attn_weights
  gemm_aw<false, float><<<NGEMM_BLK + AW_BLK, 256, 0, stream>>>(
      A16, Wpj16, b_proj, outp, nullptr, aw, AWW_END, AW_TOT4 - AWW_END, DMODEL, DMODEL);
}

// Round 9
// 542.285 us; speedup vs baseline: 1.0270x; 1.0270x over previous
//
#include <hip/hip_runtime.h>
#include <hip/hip_bf16.h>

// Problem constants (B=2, S=2048, D=1536, H=12, hd=128)
#define S_LEN   2048
#define DMODEL  1536
#define NBATCH  2
#define NHEADS  12
#define MROWS   (NBATCH * S_LEN)        // 4096
#define NCHUNK  64                      // scan chunks per sequence (32 rows each)
#define CHUNK   32

#define NGEMM_BLK  384                  // (MROWS/128) * (DMODEL/128) = 32*12
#define AW_BLK     3072                 // aw writer blocks per GEMM launch
#define WA_BLK     3072                 // winavg blocks
#define AW_BLK_W   512                  // aw writer blocks in winavg launch

// attn_weights f32x4 elements: B*H*S*S/4, split 45% / 15% / 40%
#define AW_TOT4    25165824u
#define AW1_END    11324416u            // gemm1 slice  [0, AW1_END)
#define AWW_END    15098880u            // winavg slice [AW1_END, AWW_END)

typedef unsigned short u16;
typedef __attribute__((ext_vector_type(8))) short bf16x8;   // 8 bf16 = 4 VGPRs
typedef __attribute__((ext_vector_type(4))) float f32x4;    // native vec4

// round-to-nearest-even fp32 -> bf16
__device__ __forceinline__ u16 f2bf(float x) {
  unsigned u = __float_as_uint(x);
  u += 0x7fffu + ((u >> 16) & 1u);
  return (u16)(u >> 16);
}
__device__ __forceinline__ float bf2f(u16 x) {
  return __uint_as_float(((unsigned)x) << 16);
}

// analytic attn_weights writer: grid-stride over [aw0, aw0+awcnt) f32x4 slots.
// NONTEMPORAL stores: R7 vs R8 A/B measured NT 13.6 µs faster — the 402 MB
// pure stream bypasses L2, avoiding RFO/eviction traffic alongside GEMM tiles.
__device__ __forceinline__ void aw_write(f32x4* __restrict__ aw, unsigned aw0,
                                         unsigned awcnt, unsigned bid,
                                         unsigned nblk) {
  const unsigned stride = nblk * 256u;
  const unsigned end = aw0 + awcnt;
  for (unsigned t = aw0 + bid * 256u + threadIdx.x; t < end; t += stride) {
    int j0 = (int)(t & 511u) << 2;
    int i  = (int)(t >> 9) & (S_LEN - 1);
    int bh = (int)(t >> 20);                     // S*S/4 = 2^20 per (b,h)
    int h  = bh >= NHEADS ? bh - NHEADS : bh;
    int w  = (2 << h) - 1;
    float inv = 1.0f / (float)min(i + 1, w);
    int lo = i - w + 1;
    f32x4 r;
    r.x = (j0     <= i && j0     >= lo) ? inv : 0.f;
    r.y = (j0 + 1 <= i && j0 + 1 >= lo) ? inv : 0.f;
    r.z = (j0 + 2 <= i && j0 + 2 >= lo) ? inv : 0.f;
    r.w = (j0 + 3 <= i && j0 + 3 >= lo) ? inv : 0.f;
    __builtin_nontemporal_store(r, &aw[t]);
  }
}

// ---------------------------------------------------------------- fused cvt fp32->bf16 (3 tensors)
#define N4_HID  1572864     // 2*2048*1536/4
#define N4_W    589824      // 1536*1536/4
__global__ void cvt_all(const float4* __restrict__ h, const float4* __restrict__ wf,
                        const float4* __restrict__ wp, ushort4* __restrict__ ho,
                        ushort4* __restrict__ wfo, ushort4* __restrict__ wpo) {
  int t = blockIdx.x * blockDim.x + threadIdx.x;   // N4_HID + 2*N4_W = 2752512
  const float4* src;
  ushort4* dst;
  int idx;
  if (t < N4_HID)            { src = h;  dst = ho;  idx = t; }
  else if (t < N4_HID + N4_W){ src = wf; dst = wfo; idx = t - N4_HID; }
  else                       { src = wp; dst = wpo; idx = t - N4_HID - N4_W; }
  float4 f = src[idx];
  ushort4 o;
  o.x = f2bf(f.x); o.y = f2bf(f.y); o.z = f2bf(f.z); o.w = f2bf(f.w);
  dst[idx] = o;
}

// ---------------------------------------------------------------- GEMM + attn-weights hybrid
// Blocks [0, NGEMM_BLK): m97-structure bf16 GEMM C = A@B^T + bias (128x128
// tile, BK=32, 4 waves, 16x16x32 MFMA, global_load_lds width=16).
// Blocks [NGEMM_BLK, ...): attn-weights NT stream (co-scheduled, m114).
__device__ __forceinline__ void gld_lds16(u16* lds, const u16* g) {
  __builtin_amdgcn_global_load_lds(
      (const __attribute__((address_space(1))) unsigned int*)g,
      (__attribute__((address_space(3))) unsigned int*)lds, 16, 0, 0);
}

template <bool WITH_CSUM, typename CT>
__global__ __launch_bounds__(256)
void gemm_aw(const u16* __restrict__ A, const u16* __restrict__ B,
             const float* __restrict__ bias, CT* __restrict__ C,
             float* __restrict__ cs, f32x4* __restrict__ aw,
             unsigned aw0, unsigned awcnt, int Ndim, int Kdim) {
  if ((int)blockIdx.x >= NGEMM_BLK) {
    aw_write(aw, aw0, awcnt, blockIdx.x - NGEMM_BLK, gridDim.x - NGEMM_BLK);
    return;
  }

  __shared__ __align__(16) u16 As[128 * 32];   // row-major, row stride 32 bf16 (64 B)
  __shared__ __align__(16) u16 Bs[128 * 32];
  __shared__ float colpart[4][128];            // 32-row-group column sums

  const int tid  = threadIdx.x;
  const int wave = tid >> 6;
  const int lane = tid & 63;
  const int l15  = lane & 15;
  const int quad = lane >> 4;
  const int bm = (blockIdx.x / (DMODEL / 128)) * 128;
  const int bn = (blockIdx.x % (DMODEL / 128)) * 128;
  const int wm = (wave >> 1) * 64;
  const int wn = (wave & 1) * 64;

  f32x4 acc[4][4] = {};

  const int srow = wave * 32 + (lane >> 2);
  const int skk  = (lane & 3) * 8;
  const u16* gA = A + (size_t)(bm + srow) * Kdim + skk;
  const u16* gB = B + (size_t)(bn + srow) * Kdim + skk;
  u16* lA = &As[(wave * 32) * 32];
  u16* lB = &Bs[(wave * 32) * 32];
  const size_t rstep16 = (size_t)16 * Kdim;

  for (int k0 = 0; k0 < Kdim; k0 += 32) {
    gld_lds16(lA,           gA + k0);
    gld_lds16(lA + 16 * 32, gA + k0 + rstep16);
    gld_lds16(lB,           gB + k0);
    gld_lds16(lB + 16 * 32, gB + k0 + rstep16);
    __syncthreads();

    bf16x8 af[4], bfr[4];
#pragma unroll
    for (int i = 0; i < 4; ++i)
      af[i] = *(const bf16x8*)&As[(wm + i * 16 + l15) * 32 + quad * 8];
#pragma unroll
    for (int j = 0; j < 4; ++j)
      bfr[j] = *(const bf16x8*)&Bs[(wn + j * 16 + l15) * 32 + quad * 8];
#pragma unroll
    for (int i = 0; i < 4; ++i)
#pragma unroll
      for (int j = 0; j < 4; ++j)
        acc[i][j] = __builtin_amdgcn_mfma_f32_16x16x32_bf16(af[i], bfr[j], acc[i][j], 0, 0, 0);
    __syncthreads();
  }

  // epilogue: C/D layout col = lane&15, row = quad*4 + reg   [verified m89/m91]
  const int r0 = quad * 4;
#pragma unroll
  for (int j = 0; j < 4; ++j) {
    const int col = bn + wn + j * 16 + l15;
    const float bj = bias[col];
    float sA = 0.f, sB = 0.f;     // rows [wm, wm+32) and [wm+32, wm+64)
#pragma unroll
    for (int i = 0; i < 4; ++i) {
      const int row = bm + wm + i * 16 + r0;
#pragma unroll
      for (int r = 0; r < 4; ++r) {
        float cv = acc[i][j][r] + bj;
        if constexpr (sizeof(CT) == 2)
          C[(size_t)(row + r) * Ndim + col] = (CT)f2bf(cv);
        else
          C[(size_t)(row + r) * Ndim + col] = (CT)cv;   // plain (R6's best config)
        if (WITH_CSUM) { if (i < 2) sA += cv; else sB += cv; }
      }
    }
    if (WITH_CSUM) {
      sA += __shfl_xor(sA, 16); sA += __shfl_xor(sA, 32);
      sB += __shfl_xor(sB, 16); sB += __shfl_xor(sB, 32);
      if (quad == 0) {
        colpart[(wm >> 5) | 0][wn + j * 16 + l15] = sA;
        colpart[(wm >> 5) | 1][wn + j * 16 + l15] = sB;
      }
    }
  }
  if (WITH_CSUM) {
    __syncthreads();
    if (tid < 128) {
      const int b  = bm >> 11;               // 2048 rows per batch
      const int c0 = (bm & 2047) >> 5;       // first 32-row chunk of this tile
#pragma unroll
      for (int g = 0; g < 4; ++g)
        cs[((size_t)b * NCHUNK + c0 + g) * DMODEL + bn + tid] = colpart[g][tid];
    }
  }
}

// ---------------------------------------------------------------- winavg (strip=8) + aw hybrid
// Blocks [0, WA_BLK): one thread per (b, 8-row strip, d). Chunk prefix is
// inlined: E[c0] and E[ct] (ct<=c0) accumulate in ONE pass of <=63
// INDEPENDENT L2-resident csums loads (no dependent chain, no Epre buffer).
// Blocks [WA_BLK, ...): attn-weights NT stream under winavg's latency-bound
// execution (spare HBM write BW). Branches wave-uniform.
__global__ void winavg_aw(const u16* __restrict__ v, const float* __restrict__ cs,
                          u16* __restrict__ A2, f32x4* __restrict__ aw,
                          unsigned aw0, unsigned awcnt) {
  if ((int)blockIdx.x >= WA_BLK) {
    aw_write(aw, aw0, awcnt, blockIdx.x - WA_BLK, gridDim.x - WA_BLK);
    return;
  }
  int t = blockIdx.x * blockDim.x + threadIdx.x;   // NBATCH*(S_LEN/8)*DMODEL = 786432
  int d = t % DMODEL;
  int s = (t / DMODEL) & 255;                      // strip index, S_LEN/8 = 256
  int b = t / (DMODEL * 256);
  const int h = d >> 7;
  const int w = (2 << h) - 1;                      // 2^(h+1)-1
  const u16* vb   = v  + (size_t)b * S_LEN * DMODEL + d;
  const float* csb = cs + (size_t)b * NCHUNK * DMODEL + d;

  const int i0 = s * 8;
  const int c0 = i0 >> 5;                          // lead chunk
  const bool need_trail = (i0 + 7 >= w);           // wave-uniform
  const int jf = max(i0, w) - w;                   // first trail row consumed
  const int ct = (need_trail && jf > 0) ? ((jf - 1) >> 5) : 0;   // <= c0

  // one pass: E0 = E[c0], Et = E[ct]
  float E0 = 0.f, Et = 0.f;
  for (int cc = 0; cc < c0; ++cc) {                // uniform trip, independent loads
    float cv = csb[(size_t)cc * DMODEL];
    E0 += cv;
    if (cc < ct) Et += cv;
  }

  // lead = P[i0-1]
  float lead = E0;
  for (int r = c0 * 32; r < i0; ++r)               // trip in {0,8,16,24}, uniform
    lead += bf2f(vb[(size_t)r * DMODEL]);

  // trail = P[jf-1]
  float trail = 0.f;
  if (need_trail && jf > 0) {
    trail = Et;
    for (int r = ct * 32; r < jf; ++r)             // trip <=32, uniform
      trail += bf2f(vb[(size_t)r * DMODEL]);
  }

  u16* out = A2 + ((size_t)(b * S_LEN + i0)) * DMODEL + d;
#pragma unroll
  for (int rr = 0; rr < 8; ++rr) {
    const int i = i0 + rr;
    lead += bf2f(vb[(size_t)i * DMODEL]);          // lead = P[i]
    float o;
    if (i < w) {                                   // window not yet full (uniform)
      o = lead / (float)(i + 1);
    } else {
      trail += bf2f(vb[(size_t)(i - w) * DMODEL]); // trail = P[i-w]
      o = (lead - trail) / (float)w;
    }
    out[(size_t)rr * DMODEL] = f2bf(o);
  }
}

// ---------------------------------------------------------------- launch
extern "C" void kernel_launch(void* const* d_in, const int* in_sizes, int n_in,
                              void* d_out, int out_size, void* d_ws, size_t ws_size,
                              hipStream_t stream) {
  const float* hidden = (const float*)d_in[0];
  const float* W_fc   = (const float*)d_in[1];
  const float* b_fc   = (const float*)d_in[2];
  const float* W_proj = (const float*)d_in[3];
  const float* b_proj = (const float*)d_in[4];
  float* outp = (float*)d_out;
  f32x4* aw = (f32x4*)(outp + (size_t)MROWS * DMODEL);

  // workspace layout (bytes), total 35.4 MB:
  //   0        : A16   (12,582,912)  hidden bf16, later reused as winavg-output bf16
  //   12582912 : Wfc16 ( 4,718,592)
  //   17301504 : Wpj16 ( 4,718,592)
  //   22020096 : v16   (12,582,912)  bf16 v from GEMM1
  //   34603008 : csums (   786,432)  [B, NCHUNK, D] fp32 32-row chunk sums
  char* ws = (char*)d_ws;
  u16*   A16   = (u16*)(ws);
  u16*   Wfc16 = (u16*)(ws + 12582912);
  u16*   Wpj16 = (u16*)(ws + 17301504);
  u16*   v16   = (u16*)(ws + 22020096);
  float* csums = (float*)(ws + 34603008);

  // 1) all fp32->bf16 conversions in one launch
  cvt_all<<<10752, 256, 0, stream>>>((const float4*)hidden, (const float4*)W_fc,
                                     (const float4*)W_proj, (ushort4*)A16,
                                     (ushort4*)Wfc16, (ushort4*)Wpj16);

  // 2) GEMM1 (v -> bf16, fused chunk sums) + 45% of attn_weights
  gemm_aw<true, u16><<<NGEMM_BLK + AW_BLK, 256, 0, stream>>>(
      A16, Wfc16, b_fc, v16, csums, aw, 0u, AW1_END, DMODEL, DMODEL);

  // 3) winavg (inline chunk prefix) + 15% of attn_weights
  winavg_aw<<<WA_BLK + AW_BLK_W, 256, 0, stream>>>(
      v16, csums, A16, aw, AW1_END, AWW_END - AW1_END);

  // 4) GEMM2 (out -> d_out fp32) + 40% of attn_weights
  gemm_aw<false, float><<<NGEMM_BLK + AW_BLK, 256, 0, stream>>>(
      A16, Wpj16, b_proj, outp, nullptr, aw, AWW_END, AW_TOT4 - AWW_END, DMODEL, DMODEL);
}